// Round 1
// baseline (546.801 us; speedup 1.0000x reference)
//
#include <hip/hip_runtime.h>

// Problem constants (from reference): B=2048, N=1024, C=128, M=64
constexpr int kB = 2048;
constexpr int kN = 1024;
constexpr int kC = 128;
constexpr int kM = 64;
constexpr int kC4 = kC / 4;   // float4 chunks per row = 32

// ---------------------------------------------------------------------------
// Kernel 1: out = src, full 1 GiB grid-stride float4 copy (coalesced 16B/lane)
// ---------------------------------------------------------------------------
__global__ __launch_bounds__(256) void eag_copy(const float4* __restrict__ src,
                                                float4* __restrict__ out,
                                                long long n4) {
    long long i = (long long)blockIdx.x * blockDim.x + threadIdx.x;
    long long stride = (long long)gridDim.x * blockDim.x;
    for (; i < n4; i += stride) {
        out[i] = src[i];
    }
}

// ---------------------------------------------------------------------------
// Kernel 2: per batch, overwrite each indexed row with the sum of all tar rows
// that map to it. Erase semantics => src contribution is zero for these rows,
// so a plain overwrite of the accumulated tar is exact.
// Ownership: only the FIRST occurrence m of an index value writes row idx[m],
// and it sums every duplicate — so each output row has exactly one writer.
// ---------------------------------------------------------------------------
__global__ __launch_bounds__(256) void eag_scatter(const float* __restrict__ tar,
                                                   const int* __restrict__ indices,
                                                   float* __restrict__ out) {
    const int b = blockIdx.x;
    __shared__ int idx[kM];
    const int tid = threadIdx.x;
    if (tid < kM) idx[tid] = indices[b * kM + tid];
    __syncthreads();

    const float4* tb = (const float4*)(tar + (long long)b * kM * kC);
    float4* ob = (float4*)(out + (long long)b * kN * kC);

    // Work items: (m, c4) pairs, M*C4 = 2048 items, 256 threads -> 8 iters
    for (int w = tid; w < kM * kC4; w += 256) {
        const int m  = w >> 5;        // w / 32
        const int c4 = w & 31;        // w % 32
        const int n  = idx[m];

        // Is m the first occurrence of index value n?
        bool first = true;
        for (int m2 = 0; m2 < m; ++m2) {
            if (idx[m2] == n) { first = false; break; }
        }
        if (!first) continue;

        // Sum all tar rows with this index (duplicates accumulate)
        float4 acc = {0.f, 0.f, 0.f, 0.f};
        for (int m2 = m; m2 < kM; ++m2) {
            if (idx[m2] == n) {
                float4 t = tb[m2 * kC4 + c4];
                acc.x += t.x; acc.y += t.y; acc.z += t.z; acc.w += t.w;
            }
        }
        ob[(long long)n * kC4 + c4] = acc;
    }
}

extern "C" void kernel_launch(void* const* d_in, const int* in_sizes, int n_in,
                              void* d_out, int out_size, void* d_ws, size_t ws_size,
                              hipStream_t stream) {
    const float* src     = (const float*)d_in[0];
    const float* tar     = (const float*)d_in[1];
    const int*   indices = (const int*)d_in[2];
    float*       out     = (float*)d_out;

    const long long n4 = (long long)kB * kN * kC / 4;  // 67,108,864 float4s

    // Memory-bound: cap grid ~2048 blocks, grid-stride the rest (Guideline 11)
    eag_copy<<<2048, 256, 0, stream>>>((const float4*)src, (float4*)out, n4);

    // One block per batch; stream order guarantees it runs after the copy.
    eag_scatter<<<kB, 256, 0, stream>>>(tar, indices, out);
}

// Round 2
// 429.802 us; speedup vs baseline: 1.2722x; 1.2722x over previous
//
#include <hip/hip_runtime.h>

// Problem constants (from reference): B=2048, N=1024, C=128, M=64
constexpr int kB  = 2048;
constexpr int kN  = 1024;
constexpr int kC  = 128;
constexpr int kM  = 64;
constexpr int kC4 = kC / 4;    // float4 chunks per row = 32

constexpr int RPB = 64;        // rows per block
constexpr int BPB = kN / RPB;  // row-blocks per batch = 16
constexpr int ITEMS = RPB * kC4 / 256;  // float4 items per thread = 8

// ---------------------------------------------------------------------------
// Fused erase-add gate. One block = 64 rows of one batch.
//  - LDS: the batch's 64 indices + a per-row "is indexed" flag table.
//  - Hot path: straight float4 copy with 8 unrolled loads/stores per thread
//    (8 outstanding global_load_dwordx4 -> full memory-level parallelism).
//  - Rare path (~6% of rows): overwrite register with the duplicate-
//    accumulated sum of matching tar rows (erase semantics zero out src).
// Every output element is written exactly once per call (deterministic,
// poison-safe).
// ---------------------------------------------------------------------------
__global__ __launch_bounds__(256) void eag_fused(const float4* __restrict__ src,
                                                 const float4* __restrict__ tar,
                                                 const int* __restrict__ indices,
                                                 float4* __restrict__ out) {
    const int bid  = blockIdx.x;
    const int b    = bid >> 4;          // / BPB
    const int row0 = (bid & (BPB - 1)) * RPB;
    const int tid  = threadIdx.x;

    __shared__ int idx[kM];
    __shared__ int flag[RPB];

    // Stage indices + zero flags (kM == RPB == 64)
    if (tid < kM) {
        idx[tid]  = indices[b * kM + tid];
        flag[tid] = 0;
    }
    __syncthreads();
    if (tid < kM) {
        const int rel = idx[tid] - row0;
        if (rel >= 0 && rel < RPB) flag[rel] = 1;   // benign same-value race
    }

    // Issue all 8 src loads up front (independent -> 8 in flight per thread).
    const long long base = ((long long)b * kN + row0) * kC4;
    float4 v[ITEMS];
#pragma unroll
    for (int k = 0; k < ITEMS; ++k) {
        v[k] = src[base + tid + k * 256];
    }

    __syncthreads();  // flags ready

    // Rare path: indexed rows get the accumulated tar sum instead.
    const float4* tb = tar + (long long)b * kM * kC4;
#pragma unroll
    for (int k = 0; k < ITEMS; ++k) {
        const int w = tid + k * 256;
        const int r = w >> 5;           // local row (same across a half-wave)
        if (flag[r]) {
            const int c4 = w & (kC4 - 1);
            const int n  = row0 + r;
            float4 acc = {0.f, 0.f, 0.f, 0.f};
            for (int m = 0; m < kM; ++m) {
                if (idx[m] == n) {      // broadcast LDS read, uniform per half-wave
                    const float4 t = tb[m * kC4 + c4];
                    acc.x += t.x; acc.y += t.y; acc.z += t.z; acc.w += t.w;
                }
            }
            v[k] = acc;
        }
    }

    // Store all 8 (coalesced 512B per half-wave per item).
#pragma unroll
    for (int k = 0; k < ITEMS; ++k) {
        out[base + tid + k * 256] = v[k];
    }
}

extern "C" void kernel_launch(void* const* d_in, const int* in_sizes, int n_in,
                              void* d_out, int out_size, void* d_ws, size_t ws_size,
                              hipStream_t stream) {
    const float4* src     = (const float4*)d_in[0];
    const float4* tar     = (const float4*)d_in[1];
    const int*    indices = (const int*)d_in[2];
    float4*       out     = (float4*)d_out;

    eag_fused<<<kB * BPB, 256, 0, stream>>>(src, tar, indices, out);
}

// Round 3
// 421.709 us; speedup vs baseline: 1.2966x; 1.0192x over previous
//
#include <hip/hip_runtime.h>

// Problem constants (from reference): B=2048, N=1024, C=128, M=64
constexpr int kB  = 2048;
constexpr int kN  = 1024;
constexpr int kC  = 128;
constexpr int kM  = 64;
constexpr int kC4 = kC / 4;    // float4 chunks per row = 32

constexpr int RPB = 64;        // rows per block
constexpr int BPB = kN / RPB;  // row-blocks per batch = 16
constexpr int ITEMS = RPB * kC4 / 256;  // float4 items per thread = 8

// ---------------------------------------------------------------------------
// Fused erase-add gate. One block = 64 rows of one batch.
//  - Wave 0 loads the batch's 64 indices, builds a per-row flag table AND a
//    64-bit ballot mask of which index slots m fall in this block's row range.
//  - Hot path: straight float4 copy, 8 unrolled loads/stores per thread.
//  - Rare path (~6% of rows): scan ONLY the set bits of the ballot mask
//    (expected ~4) instead of all 64 slots; accumulate matching tar rows
//    (erase semantics zero the src contribution). LSB-first = index order,
//    deterministic.
// Every output element is written exactly once per call.
// ---------------------------------------------------------------------------
__global__ __launch_bounds__(256) void eag_fused(const float4* __restrict__ src,
                                                 const float4* __restrict__ tar,
                                                 const int* __restrict__ indices,
                                                 float4* __restrict__ out) {
    const int bid  = blockIdx.x;
    const int b    = bid >> 4;               // / BPB
    const int row0 = (bid & (BPB - 1)) * RPB;
    const int tid  = threadIdx.x;

    __shared__ int idx[kM];
    __shared__ int flag[RPB];
    __shared__ unsigned long long smask;

    // Wave 0 (tid 0..63) handles all index bookkeeping; kM == wave width.
    if (tid < kM) {
        const int my = indices[b * kM + tid];
        idx[tid]  = my;
        flag[tid] = 0;                       // same-wave ds ops are ordered
        const int rel = my - row0;
        const bool local = (rel >= 0) && (rel < RPB);
        const unsigned long long mb = __ballot(local);
        if (tid == 0) smask = mb;
        if (local) flag[rel] = 1;
    }

    // Issue all 8 src loads up front (independent -> 8 in flight per thread).
    const long long base = ((long long)b * kN + row0) * kC4;
    float4 v[ITEMS];
#pragma unroll
    for (int k = 0; k < ITEMS; ++k) {
        v[k] = src[base + tid + k * 256];
    }

    __syncthreads();  // idx/flag/smask ready
    const unsigned long long lmask = smask;

    // Rare path: indexed rows get the accumulated tar sum instead.
    const float4* tb = tar + (long long)b * kM * kC4;
#pragma unroll
    for (int k = 0; k < ITEMS; ++k) {
        const int w = tid + k * 256;
        const int r = w >> 5;                // local row (uniform per half-wave)
        if (flag[r]) {
            const int c4 = w & (kC4 - 1);
            const int n  = row0 + r;
            float acx = 0.f, acy = 0.f, acz = 0.f, acw = 0.f;
            for (unsigned long long mm = lmask; mm; mm &= mm - 1) {
                const int m = (int)__builtin_ctzll(mm);
                if (idx[m] == n) {
                    const float4 t = tb[m * kC4 + c4];
                    acx += t.x; acy += t.y; acz += t.z; acw += t.w;
                }
            }
            v[k].x = acx; v[k].y = acy; v[k].z = acz; v[k].w = acw;
        }
    }

    // Store all 8 (coalesced 512B per half-wave per item).
#pragma unroll
    for (int k = 0; k < ITEMS; ++k) {
        out[base + tid + k * 256] = v[k];
    }
}

extern "C" void kernel_launch(void* const* d_in, const int* in_sizes, int n_in,
                              void* d_out, int out_size, void* d_ws, size_t ws_size,
                              hipStream_t stream) {
    const float4* src     = (const float4*)d_in[0];
    const float4* tar     = (const float4*)d_in[1];
    const int*    indices = (const int*)d_in[2];
    float4*       out     = (float4*)d_out;

    eag_fused<<<kB * BPB, 256, 0, stream>>>(src, tar, indices, out);
}